// Round 1
// 203.154 us; speedup vs baseline: 1.0062x; 1.0062x over previous
//
#include <hip/hip_runtime.h>

// 1024-point FFT of real input, batched 16384. Two-for-one packing:
// each block handles TWO rows as one complex sequence z = x0 + i*x1,
// runs a radix-4 Stockham DIF FFT (5 stages, 256 threads, one butterfly
// per thread per stage), then unpacks both spectra via conjugate symmetry
// and stores natural-order coalesced.
//
// This revision vectorizes ALL global I/O to 16 B/lane:
//  - input rows staged via float4 loads into LDS (bufB reused), stage 0
//    reads the staged reals (4B-stride LDS reads, 2-way = free)
//  - twiddles loaded as float4 by 128 threads
//  - unpack restructured so each thread owns 4 consecutive k and emits
//    4x float4 nontemporal stores (output is write-once)
//  - stage 4 specialized: STEP=0 => unit twiddles, skip cmul + tw reads
//
// Exact twiddles from input tw_real_3/tw_imag_3 (= w_1024^k, k<512),
// extended to k<1024 by negation.

#define N_FFT 1024
#define BATCH 16384
#define TPB   256

typedef float f4 __attribute__((ext_vector_type(4)));

// LDS pad: +1 float2 per 16 slots -> strided write patterns spread over banks
__device__ __forceinline__ int pad16(int a) { return a + (a >> 4); }

__device__ __forceinline__ float2 cmul(float2 a, float2 b) {
    return make_float2(a.x * b.x - a.y * b.y, a.x * b.y + a.y * b.x);
}

// One radix-4 DIF butterfly + twiddle + strided store to LDS.
// Thread tid owns (j = tid/M, k = tid%M); inputs are x[tid + q*256].
template<int M, int STEP, bool UNIT_TW>
__device__ __forceinline__ void butterfly_store(float2 a, float2 b, float2 c, float2 d,
                                                float2* __restrict__ dst,
                                                const float2* __restrict__ tw,
                                                int tid)
{
    const int j = tid / M;
    const int k = tid % M;
    float2 t0 = make_float2(a.x + c.x, a.y + c.y);
    float2 t1 = make_float2(a.x - c.x, a.y - c.y);
    float2 t2 = make_float2(b.x + d.x, b.y + d.y);
    float2 t3 = make_float2(b.y - d.y, d.x - b.x);   // -i*(b-d)
    float2 y0 = make_float2(t0.x + t2.x, t0.y + t2.y);
    float2 u1 = make_float2(t1.x + t3.x, t1.y + t3.y);
    float2 u2 = make_float2(t0.x - t2.x, t0.y - t2.y);
    float2 u3 = make_float2(t1.x - t3.x, t1.y - t3.y);
    const int base = 4 * M * j + k;
    if (UNIT_TW) {
        // STEP*j == 0 for all threads: w1=w2=w3=(1,0)
        dst[pad16(base)]         = y0;
        dst[pad16(base + M)]     = u1;
        dst[pad16(base + 2 * M)] = u2;
        dst[pad16(base + 3 * M)] = u3;
    } else {
        float2 w1 = tw[STEP * j];
        float2 w2 = tw[2 * STEP * j];
        float2 w3 = tw[3 * STEP * j];
        dst[pad16(base)]         = y0;
        dst[pad16(base + M)]     = cmul(u1, w1);
        dst[pad16(base + 2 * M)] = cmul(u2, w2);
        dst[pad16(base + 3 * M)] = cmul(u3, w3);
    }
}

template<int M, int STEP, bool UNIT_TW>
__device__ __forceinline__ void stage_mid(const float2* __restrict__ src,
                                          float2* __restrict__ dst,
                                          const float2* __restrict__ tw,
                                          int tid)
{
    float2 a = src[pad16(tid)];
    float2 b = src[pad16(tid + 256)];
    float2 c = src[pad16(tid + 512)];
    float2 d = src[pad16(tid + 768)];
    butterfly_store<M, STEP, UNIT_TW>(a, b, c, d, dst, tw, tid);
}

__global__ __launch_bounds__(TPB) void fft1024_kernel(
    const float* __restrict__ x,
    const float* __restrict__ twr,   // w_1024^k re, k<512
    const float* __restrict__ twi,   // w_1024^k im, k<512
    float* __restrict__ outr,
    float* __restrict__ outi)
{
    __shared__ __align__(16) float2 bufA[1088];   // 1024 + 64 pad slots
    __shared__ __align__(16) float2 bufB[1088];
    __shared__ __align__(16) float2 tw[1024];

    const int tid = threadIdx.x;
    const long long r0 = 2LL * blockIdx.x;      // even row; odd row = r0+1

    // ---- stage the two input rows (2048 floats) via float4 into bufB ----
    {
        const f4* __restrict__ xv = reinterpret_cast<const f4*>(x + r0 * N_FFT);
        f4* xs = reinterpret_cast<f4*>(bufB);
        xs[tid]       = xv[tid];        // floats [0,1024)   = row r0
        xs[tid + 256] = xv[tid + 256];  // floats [1024,2048) = row r0+1
    }
    // ---- twiddles: float4 loads, first 128 threads cover 512 entries ----
    if (tid < 128) {
        f4 re = reinterpret_cast<const f4*>(twr)[tid];
        f4 im = reinterpret_cast<const f4*>(twi)[tid];
        #pragma unroll
        for (int j = 0; j < 4; ++j) {
            tw[4 * tid + j]       = make_float2(re[j], im[j]);
            tw[4 * tid + j + 512] = make_float2(-re[j], -im[j]);
        }
    }
    __syncthreads();

    // ---- stage 0: m=1, complex input z = x0 + i*x1, from staged LDS ----
    {
        const float* xs = reinterpret_cast<const float*>(bufB);
        float2 a = make_float2(xs[tid],       xs[tid + 1024]);
        float2 b = make_float2(xs[tid + 256], xs[tid + 1280]);
        float2 c = make_float2(xs[tid + 512], xs[tid + 1536]);
        float2 d = make_float2(xs[tid + 768], xs[tid + 1792]);
        butterfly_store<1, 1, false>(a, b, c, d, bufA, tw, tid);
    }
    __syncthreads();

    stage_mid<4, 4, false>(bufA, bufB, tw, tid);     // stage 1
    __syncthreads();
    stage_mid<16, 16, false>(bufB, bufA, tw, tid);   // stage 2
    __syncthreads();
    stage_mid<64, 64, false>(bufA, bufB, tw, tid);   // stage 3
    __syncthreads();
    stage_mid<256, 0, true>(bufB, bufA, tw, tid);    // stage 4: unit twiddles
    __syncthreads();

    // ---- unpack two real-input spectra, 4 consecutive k per thread,
    //      store as float4 nontemporal (write-once stream) ----
    f4* or0v = reinterpret_cast<f4*>(outr + r0 * N_FFT);
    f4* oi0v = reinterpret_cast<f4*>(outi + r0 * N_FFT);
    f4 vr0, vi0, vr1, vi1;
    #pragma unroll
    for (int j = 0; j < 4; ++j) {
        const int k  = 4 * tid + j;
        const int nk = (N_FFT - k) & (N_FFT - 1);
        float2 zk = bufA[pad16(k)];
        float2 zn = bufA[pad16(nk)];
        // X0 = (Z(k) + conj(Z(-k)))/2 ; X1 = -i*(Z(k) - conj(Z(-k)))/2
        vr0[j] = 0.5f * (zk.x + zn.x);
        vi0[j] = 0.5f * (zk.y - zn.y);
        vr1[j] = 0.5f * (zk.y + zn.y);
        vi1[j] = 0.5f * (zn.x - zk.x);
    }
    __builtin_nontemporal_store(vr0, or0v + tid);         // row r0 real
    __builtin_nontemporal_store(vi0, oi0v + tid);         // row r0 imag
    __builtin_nontemporal_store(vr1, or0v + 256 + tid);   // row r0+1 real
    __builtin_nontemporal_store(vi1, oi0v + 256 + tid);   // row r0+1 imag
}

extern "C" void kernel_launch(void* const* d_in, const int* in_sizes, int n_in,
                              void* d_out, int out_size, void* d_ws, size_t ws_size,
                              hipStream_t stream) {
    // setup_inputs order:
    // 0:x 1:perm 2:fft_real 3:fft_imag 4..11: tw_{real,imag}_{0..3}
    const float* x   = (const float*)d_in[0];
    const float* twr = (const float*)d_in[10];  // 512 entries: w_1024^k real
    const float* twi = (const float*)d_in[11];  // 512 entries: w_1024^k imag
    float* outr = (float*)d_out;
    float* outi = outr + (size_t)BATCH * N_FFT;
    fft1024_kernel<<<BATCH / 2, TPB, 0, stream>>>(x, twr, twi, outr, outi);
}